// Round 8
// baseline (357.052 us; speedup 1.0000x reference)
//
#include <hip/hip_runtime.h>
#include <hip/hip_bf16.h>

#define D_MODEL 4096
#define NFIB    64
#define NBATCH  4
#define LSEQ    4096

typedef __attribute__((ext_vector_type(4))) float f32x4;
typedef __attribute__((ext_vector_type(8))) short bf16x8;

__device__ __forceinline__ unsigned short f2bf(float f) {
  unsigned int u = __builtin_bit_cast(unsigned int, f);
  u += 0x7FFFu + ((u >> 16) & 1u);
  return (unsigned short)(u >> 16);
}

__device__ __forceinline__ bf16x8 cvt8(f32x4 a, f32x4 b) {
  union { __hip_bfloat162 h2[4]; bf16x8 v; } u;
  u.h2[0] = __float22bfloat162_rn(make_float2(a[0], a[1]));
  u.h2[1] = __float22bfloat162_rn(make_float2(a[2], a[3]));
  u.h2[2] = __float22bfloat162_rn(make_float2(b[0], b[1]));
  u.h2[3] = __float22bfloat162_rn(make_float2(b[2], b[3]));
  return u.v;
}

// ---------------------------------------------------------------------------
// Blocks 0..3: S_b = Q_b - I = 2(I-A)^{-1}A (Gauss-Jordan, 2 barriers/pivot).
// Blocks 4..1027: W_down -> bf16 wave-swizzled Wd2.
// ---------------------------------------------------------------------------
__global__ __launch_bounds__(256) void prep1_kernel(const float* __restrict__ A,
                                                    const float* __restrict__ Wd,
                                                    float* __restrict__ S,
                                                    unsigned short* __restrict__ Wd2) {
  const int blk = blockIdx.x;
  if (blk >= NBATCH) {
    int idx = (blk - NBATCH) * 256 + threadIdx.x;
    int j    = idx & 7;
    int lane = (idx >> 3) & 63;
    int nf   = (idx >> 9) & 3;
    int ks   = idx >> 11;
    int row = nf * 16 + (lane & 15);
    int col = ks * 32 + (lane >> 4) * 8 + j;
    Wd2[idx] = f2bf(Wd[row * D_MODEL + col]);
    return;
  }
  __shared__ float M[64][66];
  __shared__ float R[64][66];
  const int b = blk;
  const int tid = threadIdx.x;
  const int k = tid & 63;
  const int g = tid >> 6;
  const float* Ab = A + b * 4096;
#pragma unroll
  for (int ii = 0; ii < 16; ++ii) {
    int i = g * 16 + ii;
    float a = Ab[i * 64 + k];
    M[i][k] = ((i == k) ? 1.0f : 0.0f) - a;
    R[i][k] = 2.0f * a;
  }
  for (int j = 0; j < 64; ++j) {
    __syncthreads();
    float pr  = 1.0f / M[j][j];
    float mjk = M[j][k], rjk = R[j][k];
    float f[16];
#pragma unroll
    for (int ii = 0; ii < 16; ++ii) f[ii] = M[g * 16 + ii][j] * pr;
    __syncthreads();
#pragma unroll
    for (int ii = 0; ii < 16; ++ii) {
      int i = g * 16 + ii;
      if (i != j) { M[i][k] -= f[ii] * mjk; R[i][k] -= f[ii] * rjk; }
    }
  }
  __syncthreads();
  float* Sb = S + b * 4096;
#pragma unroll
  for (int ii = 0; ii < 16; ++ii) {
    int i = g * 16 + ii;
    Sb[i * 64 + k] = R[i][k] / M[i][i];
  }
}

// ---------------------------------------------------------------------------
// U2[(((b*256+nt)*64+lane)*2+h)*8+j] = bf16(alpha*(Wup@S)[d][f]),
//   d = nt*16+(lane&15), f = h*32+(lane>>4)*8+j.
// ---------------------------------------------------------------------------
__global__ __launch_bounds__(256) void prep_u_kernel(const float* __restrict__ Wup,
                                                     const float* __restrict__ S,
                                                     const float* __restrict__ alpha_p,
                                                     unsigned short* __restrict__ U2) {
  __shared__ float Sl[4096];
  const int blk = blockIdx.x;          // 0..511
  const int b = blk >> 7;
  const int ntg = blk & 127;           // 2 nt per block
  const float* Sb = S + b * 4096;
  for (int i = threadIdx.x; i < 1024; i += 256)
    ((f32x4*)Sl)[i] = ((const f32x4*)Sb)[i];
  __syncthreads();

  const int t = threadIdx.x;
  const int nt   = ntg * 2 + (t >> 7);
  const int h    = (t >> 6) & 1;
  const int lane = t & 63;
  const int d = nt * 16 + (lane & 15);
  const int fbase = h * 32 + (lane >> 4) * 8;
  const float alpha = alpha_p[0];
  const f32x4* wr = (const f32x4*)(Wup + d * 64);

  float s[8];
#pragma unroll
  for (int j = 0; j < 8; ++j) s[j] = 0.f;
#pragma unroll
  for (int g4 = 0; g4 < 16; ++g4) {
    f32x4 wv = wr[g4];
#pragma unroll
    for (int gg = 0; gg < 4; ++gg) {
      const float* srow = &Sl[(g4 * 4 + gg) * 64 + fbase];
      float wvg = wv[gg];
#pragma unroll
      for (int j = 0; j < 8; ++j) s[j] += wvg * srow[j];
    }
  }
  bf16x8 v;
#pragma unroll
  for (int j = 0; j < 8; ++j) v[j] = (short)f2bf(alpha * s[j]);
  *(bf16x8*)(U2 + ((((size_t)b * 256 + nt) * 64 + lane) * 2 + h) * 8) = v;
}

// ---------------------------------------------------------------------------
// P1: F = H @ Wd^T.  1024 blocks x 256 thr (4 waves), 16 tokens/block.
// NO LDS, NO barriers. Burst-4 structure: issue 12 independent load
// instructions (8x A-fragment f32x4 from H, 4x B-fragment bf16x8 from
// L2-hot Wd2), sched_barrier fence, then 4x (cvt8 + MFMA). The fence pins
// the whole load group ahead of the compute so ~11 loads stay in flight
// during the first-use waitcnt (R3/R6 failure: compiler sank loads to
// just-before-use, 1 in flight). Wave w owns fibers w*16..w*16+15.
// ---------------------------------------------------------------------------
__global__ __launch_bounds__(256, 4) void p1_kernel(
    const float* __restrict__ H, const unsigned short* __restrict__ Wd2,
    unsigned short* __restrict__ F2) {
  const int blk = blockIdx.x;
  const int row0 = blk * 16;
  const int tid = threadIdx.x;
  const int w = tid >> 6, l = tid & 63, lr = l & 15, lq = l >> 4;

  // A-fragment: row = lane&15 (token), k = (lane>>4)*8 + j
  const float* ha = H + (size_t)(row0 + lr) * D_MODEL + lq * 8;
  // B-fragment for step s, wave w: Wd2 + (s*256 + w*64 + l)*8
  const unsigned short* wb = Wd2 + ((size_t)w * 64 + l) * 8;

  f32x4 acc = {0, 0, 0, 0};

  for (int sb = 0; sb < 32; ++sb) {
    const float* hp = ha + sb * 128;            // 4 steps * 32 cols
    const unsigned short* wp = wb + (size_t)sb * 8192;  // 4 steps * 2048
    f32x4 a0[4], a1[4];
    bf16x8 bfr[4];
#pragma unroll
    for (int u = 0; u < 4; ++u) {
      a0[u] = *(const f32x4*)(hp + u * 32);
      a1[u] = *(const f32x4*)(hp + u * 32 + 4);
      bfr[u] = *(const bf16x8*)(wp + u * 2048);
    }
    __builtin_amdgcn_sched_barrier(0);
#pragma unroll
    for (int u = 0; u < 4; ++u)
      acc = __builtin_amdgcn_mfma_f32_16x16x32_bf16(cvt8(a0[u], a1[u]), bfr[u], acc, 0, 0, 0);
    __builtin_amdgcn_sched_barrier(0);
  }

  // D layout: col(lane&15)=fiber, row(4*lq+reg)=token
#pragma unroll
  for (int rr = 0; rr < 4; ++rr)
    F2[(size_t)(row0 + lq * 4 + rr) * 64 + w * 16 + lr] = f2bf(acc[rr]);
}

// ---------------------------------------------------------------------------
// P2: Out = H + F @ U^T.  4096 blocks x 256 thr, no LDS, no barriers.
// Block = (16-token tile, 1024-col chunk); wave = 256-col strip (16 nf).
// Burst-4: 12 loads (4x {u0,u1 from L2-hot U2, residual H}), fence,
// 4x (2 MFMA + add + store). Stores are older than the next burst's loads
// in the vmcnt queue, so waiting for loads implies stores retired.
// ---------------------------------------------------------------------------
__global__ __launch_bounds__(256, 4) void p2_kernel(
    const float* __restrict__ H, const unsigned short* __restrict__ F2,
    const unsigned short* __restrict__ U2, float* __restrict__ Out) {
  const int blk = blockIdx.x;
  const int tile = blk >> 2;
  const int ch = blk & 3;
  const int row0 = tile * 16;
  const int b = tile >> 8;
  const int tid = threadIdx.x;
  const int w = tid >> 6, l = tid & 63, lr = l & 15, lq = l >> 4;

  const int cbase = ch * 1024 + w * 256;
  const int nt0 = cbase >> 4;

  bf16x8 fb0 = *(const bf16x8*)(F2 + (size_t)(row0 + lr) * 64 + lq * 8);
  bf16x8 fb1 = *(const bf16x8*)(F2 + (size_t)(row0 + lr) * 64 + 32 + lq * 8);

  const unsigned short* ub = U2 + (((size_t)b * 256 + nt0) * 64 + l) * 16;
  const size_t obase = (size_t)(row0 + lr) * D_MODEL + cbase + lq * 4;

  for (int nb = 0; nb < 4; ++nb) {
    const unsigned short* up = ub + (size_t)nb * 4096;
    const float* hp = H + obase + nb * 64;
    bf16x8 u0r[4], u1r[4];
    f32x4 hr[4];
#pragma unroll
    for (int u = 0; u < 4; ++u) {
      u0r[u] = *(const bf16x8*)(up + u * 1024);
      u1r[u] = *(const bf16x8*)(up + u * 1024 + 8);
      hr[u]  = *(const f32x4*)(hp + u * 16);
    }
    __builtin_amdgcn_sched_barrier(0);
#pragma unroll
    for (int u = 0; u < 4; ++u) {
      f32x4 c = {0, 0, 0, 0};
      c = __builtin_amdgcn_mfma_f32_16x16x32_bf16(u0r[u], fb0, c, 0, 0, 0);
      c = __builtin_amdgcn_mfma_f32_16x16x32_bf16(u1r[u], fb1, c, 0, 0, 0);
      *(f32x4*)(Out + obase + (nb * 4 + u) * 16) = hr[u] + c;
    }
    __builtin_amdgcn_sched_barrier(0);
  }
}

// ---------------------------------------------------------------------------
extern "C" void kernel_launch(void* const* d_in, const int* in_sizes, int n_in,
                              void* d_out, int out_size, void* d_ws, size_t ws_size,
                              hipStream_t stream) {
  const float* h_t    = (const float*)d_in[0];
  // d_in[1] = z0 (unused by the reference)
  const float* A_u    = (const float*)d_in[2];
  const float* alpha  = (const float*)d_in[3];
  const float* W_down = (const float*)d_in[4];
  const float* W_up   = (const float*)d_in[5];
  float* out = (float*)d_out;

  char* ws = (char*)d_ws;
  float*          S   = (float*)ws;                               // 64 KiB
  unsigned short* Wd2 = (unsigned short*)(ws + (64 << 10));       // 512 KiB
  unsigned short* U2  = (unsigned short*)(ws + (576 << 10));      // 2 MiB
  unsigned short* F2  = (unsigned short*)(ws + (2624 << 10));     // 2 MiB

  prep1_kernel<<<NBATCH + 1024, 256, 0, stream>>>(A_u, W_down, S, Wd2);
  prep_u_kernel<<<512, 256, 0, stream>>>(W_up, S, alpha, U2);
  p1_kernel<<<1024, 256, 0, stream>>>(h_t, Wd2, F2);
  p2_kernel<<<4096, 256, 0, stream>>>(h_t, F2, U2, out);
}